// Round 9
// baseline (198.426 us; speedup 1.0000x reference)
//
#include <hip/hip_runtime.h>
#include <hip/hip_bf16.h>

typedef __bf16 bf16;
typedef __bf16 bf16x8 __attribute__((ext_vector_type(8)));
typedef __bf16 bf16x4 __attribute__((ext_vector_type(4)));
typedef float f32x4 __attribute__((ext_vector_type(4)));

constexpr int DM = 1024, NH = 16, DH = 64, NB = 2, SQ = 2048;
constexpr int MTOT = NB * SQ;  // 4096
// Q is pre-scaled by 1/sqrt(DH) * log2(e) so attn does bare exp2(S).
constexpr float QSCALE = 0.125f * 1.44269504088896f;

// async global->LDS, 16B per lane; LDS dest is wave-uniform base + lane*16 (HW rule)
__device__ __forceinline__ void gld_lds16(const bf16* g, bf16* l) {
  __builtin_amdgcn_global_load_lds(
      (const __attribute__((address_space(1))) void*)g,
      (__attribute__((address_space(3))) void*)l, 16, 0, 0);
}

// ============ fp32 -> bf16 conversion: 4x W (1M elts each) + x (4M elts) ============
__global__ __launch_bounds__(256) void cvt5(
    const float* __restrict__ s0, const float* __restrict__ s1,
    const float* __restrict__ s2, const float* __restrict__ s3,
    const float* __restrict__ s4,
    bf16* __restrict__ d0, bf16* __restrict__ d1, bf16* __restrict__ d2,
    bf16* __restrict__ d3, bf16* __restrict__ d4) {
  const float* src; bf16* dst; int n;
  switch (blockIdx.y) {
    case 0: src = s0; dst = d0; n = DM * DM; break;
    case 1: src = s1; dst = d1; n = DM * DM; break;
    case 2: src = s2; dst = d2; n = DM * DM; break;
    case 3: src = s3; dst = d3; n = DM * DM; break;
    default: src = s4; dst = d4; n = MTOT * DM; break;
  }
  const int idx = (blockIdx.x * 256 + threadIdx.x) * 4;
  if (idx < n) {
    const float4 v = *(const float4*)(src + idx);
    *(bf16x4*)(dst + idx) = (bf16x4){(bf16)v.x, (bf16)v.y, (bf16)v.z, (bf16)v.w};
  }
}

// ========= FUSED QKV projection: one block -> 128x128 tiles of Q, K, AND V^T =========
// grid (32, 8): m0 = seq block, n0 = dm block. 256 blocks = 1/CU, single round.
// Key trick: A-frag and B-frag per-lane layouts are IDENTICAL, so the xb fragments
// loaded as the A-operand for Q/K are reused unchanged as the B-operand of the
// operand-swapped V^T GEMM (accv = mfma(vF, xF)). Per kk: 16 LDS b128 reads feed
// 48 MFMAs -> 48 MACs/LDS-byte (3x the 64x64 wave-tile ratio; GEMM was LDS-pipe
// bound). 192 acc VGPRs -> launch_bounds(256,1) (1 wave/SIMD, ~290 VGPR, no spill).
// Double-buffered staging (128 KB LDS), 1 barrier/iter.
__global__ __launch_bounds__(256, 1) void qkv_fused(
    const bf16* __restrict__ xb, const bf16* __restrict__ Wqb,
    const bf16* __restrict__ Wkb, const bf16* __restrict__ Wvb,
    const float* __restrict__ bq, const float* __restrict__ bk,
    const float* __restrict__ bv,
    bf16* __restrict__ Qw, bf16* __restrict__ Kw, bf16* __restrict__ VTw) {
  __shared__ alignas(16) bf16 sX[2][128 * 64];
  __shared__ alignas(16) bf16 sQ[2][128 * 64];
  __shared__ alignas(16) bf16 sK[2][128 * 64];
  __shared__ alignas(16) bf16 sV[2][128 * 64];
  const int tid = threadIdx.x;
  const int wave = tid >> 6, lane = tid & 63;
  const int wm = wave >> 1, wn = wave & 1;
  const int quad = lane >> 4, l16 = lane & 15;
  const int m0 = blockIdx.x * 128, n0 = blockIdx.y * 128;

  const int srow = lane >> 3;                 // 0..7
  const int scol = ((lane & 7) ^ srow) * 8;   // swizzled global chunk

  auto stage = [&](int kt, int buf) {
#pragma unroll
    for (int i = 0; i < 4; i++) {
      const int r = i * 32 + wave * 8;
      gld_lds16(xb + (size_t)(m0 + r + srow) * DM + kt + scol, &sX[buf][r * 64]);
      gld_lds16(Wqb + (size_t)(n0 + r + srow) * DM + kt + scol, &sQ[buf][r * 64]);
      gld_lds16(Wkb + (size_t)(n0 + r + srow) * DM + kt + scol, &sK[buf][r * 64]);
      gld_lds16(Wvb + (size_t)(n0 + r + srow) * DM + kt + scol, &sV[buf][r * 64]);
    }
  };

  f32x4 accq[4][4], acck[4][4], accv[4][4];
#pragma unroll
  for (int i = 0; i < 4; i++)
#pragma unroll
    for (int j = 0; j < 4; j++) {
      accq[i][j] = (f32x4){0.f, 0.f, 0.f, 0.f};
      acck[i][j] = (f32x4){0.f, 0.f, 0.f, 0.f};
      accv[i][j] = (f32x4){0.f, 0.f, 0.f, 0.f};
    }

  stage(0, 0);
  for (int it = 0; it < 16; it++) {
    __syncthreads();  // drains loads issued at it-1 (full compute phase in flight)
    if (it + 1 < 16) stage((it + 1) * 64, (it + 1) & 1);
    const bf16* cX = sX[it & 1];
    const bf16* cQ = sQ[it & 1];
    const bf16* cK = sK[it & 1];
    const bf16* cV = sV[it & 1];
#pragma unroll
    for (int kk = 0; kk < 64; kk += 32) {
      const int slot = (((kk >> 3) + quad) ^ (l16 & 7)) << 3;
      bf16x8 xF[4], qF[4], kF[4], vF[4];
#pragma unroll
      for (int i = 0; i < 4; i++) {
        xF[i] = *(const bf16x8*)&cX[(wm * 64 + i * 16 + l16) * 64 + slot];
        qF[i] = *(const bf16x8*)&cQ[(wn * 64 + i * 16 + l16) * 64 + slot];
        kF[i] = *(const bf16x8*)&cK[(wn * 64 + i * 16 + l16) * 64 + slot];
        vF[i] = *(const bf16x8*)&cV[(wn * 64 + i * 16 + l16) * 64 + slot];
      }
#pragma unroll
      for (int mt = 0; mt < 4; mt++)
#pragma unroll
        for (int nt = 0; nt < 4; nt++) {
          accq[mt][nt] = __builtin_amdgcn_mfma_f32_16x16x32_bf16(xF[mt], qF[nt], accq[mt][nt], 0, 0, 0);
          acck[mt][nt] = __builtin_amdgcn_mfma_f32_16x16x32_bf16(xF[mt], kF[nt], acck[mt][nt], 0, 0, 0);
          // V^T: operand-swapped, xF reused as B-operand
          accv[mt][nt] = __builtin_amdgcn_mfma_f32_16x16x32_bf16(vF[mt], xF[nt], accv[mt][nt], 0, 0, 0);
        }
    }
  }

  // epilogues (C/D layout: col=lane&15, row=quad*4+reg)
#pragma unroll
  for (int mt = 0; mt < 4; mt++) {
#pragma unroll
    for (int nt = 0; nt < 4; nt++) {
#pragma unroll
      for (int r = 0; r < 4; r++) {
        {  // Q, K: row = seq (m0 + wm-half), col = dm (n0 + wn-half)
          const int row = m0 + wm * 64 + mt * 16 + quad * 4 + r;
          const int col = n0 + wn * 64 + nt * 16 + l16;
          Qw[(size_t)row * DM + col] = (bf16)((accq[mt][nt][r] + bq[col]) * QSCALE);
          Kw[(size_t)row * DM + col] = (bf16)(acck[mt][nt][r] + bk[col]);
        }
        {  // V^T: row = dm (n0 + wn-half, from vF), col = seq (m0 + wm-half, from xF)
          const int row = n0 + wn * 64 + mt * 16 + quad * 4 + r;
          const int col = m0 + wm * 64 + nt * 16 + l16;
          VTw[(size_t)row * MTOT + col] = (bf16)(accv[mt][nt][r] + bv[row]);
        }
      }
    }
  }
}

// ======== GEMM-NT tile body (out projection): C = (A * B^T + bias), BM x 128 ========
template <int BM, typename OutT>
__device__ __forceinline__ void gemm_tile(
    const bf16* __restrict__ A, const bf16* __restrict__ Bm,
    const float* __restrict__ bias, OutT* __restrict__ C,
    int rowA0, int rowB0, int N, int K, bf16* sA, bf16* sB) {
  constexpr int NT = (BM == 128) ? 4 : 2;
  const int tid = threadIdx.x;
  const int wave = tid >> 6, lane = tid & 63;
  const int quad = lane >> 4, l16 = lane & 15;
  const int row0w = (BM == 128) ? (wave >> 1) * 64 : 0;
  const int col0w = (BM == 128) ? (wave & 1) * 64 : wave * 32;

  f32x4 acc[4][NT];
#pragma unroll
  for (int i = 0; i < 4; i++)
#pragma unroll
    for (int j = 0; j < NT; j++) acc[i][j] = (f32x4){0.f, 0.f, 0.f, 0.f};

  const int srow = lane >> 3;
  const int scol = ((lane & 7) ^ srow) * 8;

  for (int kt = 0; kt < K; kt += 64) {
#pragma unroll
    for (int i = 0; i < BM / 32; i++) {
      const int r = i * 32 + wave * 8;
      gld_lds16(A + (size_t)(rowA0 + r + srow) * K + kt + scol, &sA[r * 64]);
    }
#pragma unroll
    for (int i = 0; i < 4; i++) {
      const int r = i * 32 + wave * 8;
      gld_lds16(Bm + (size_t)(rowB0 + r + srow) * K + kt + scol, &sB[r * 64]);
    }
    __syncthreads();
#pragma unroll
    for (int kk = 0; kk < 64; kk += 32) {
      bf16x8 aF[4], bF[NT];
      const int slot = (((kk >> 3) + quad) ^ (l16 & 7)) << 3;
#pragma unroll
      for (int mt = 0; mt < 4; mt++)
        aF[mt] = *(const bf16x8*)&sA[(row0w + mt * 16 + l16) * 64 + slot];
#pragma unroll
      for (int nt = 0; nt < NT; nt++)
        bF[nt] = *(const bf16x8*)&sB[(col0w + nt * 16 + l16) * 64 + slot];
#pragma unroll
      for (int mt = 0; mt < 4; mt++)
#pragma unroll
        for (int nt = 0; nt < NT; nt++)
          acc[mt][nt] = __builtin_amdgcn_mfma_f32_16x16x32_bf16(aF[mt], bF[nt], acc[mt][nt], 0, 0, 0);
    }
    __syncthreads();
  }

#pragma unroll
  for (int mt = 0; mt < 4; mt++) {
#pragma unroll
    for (int nt = 0; nt < NT; nt++) {
#pragma unroll
      for (int r = 0; r < 4; r++) {
        const int row = rowA0 + row0w + mt * 16 + quad * 4 + r;
        const int col = rowB0 + col0w + nt * 16 + l16;
        C[(size_t)row * N + col] = (OutT)(acc[mt][nt][r] + bias[col]);
      }
    }
  }
}

// Output projection: BM=64 tiles -> grid (64, 8) = 512 blocks -> 2 blocks/CU.
__global__ __launch_bounds__(256, 4) void out_gemm(
    const bf16* __restrict__ A, const bf16* __restrict__ Bm,
    const float* __restrict__ bias, float* __restrict__ C) {
  __shared__ alignas(16) bf16 sA[64 * 64];
  __shared__ alignas(16) bf16 sB[128 * 64];
  gemm_tile<64, float>(A, Bm, bias, C, blockIdx.x * 64, blockIdx.y * 128, DM, DM, sA, sB);
}

// ================= Flash attention (no-max softmax, S^T orientation) =================
// grid: (hb=32, qt=16); linear block id ≡ hb (mod 8) -> all 16 qt-blocks of one (b,h)
// share an XCD (K/V stay L2-resident). Q tile 128x64 in REGISTERS. 16 KV tiles of 128,
// double-buffered, 1 barrier/tile. S^T = K*Q^T (operand swap): lane holds 4 contiguous
// kv -> packed b64 P-stores, per-lane scalar l accumulation (q = l16; l-via-MFMA was
// measured SLOWER in R8 - MFMA pipe and VALU are balanced, don't shift work to MFMA).
// sK/sV/sP XOR-swizzled at 16B granularity. LDS = 80 KB -> 2 blocks/CU (= grid cap).
__global__ __launch_bounds__(256, 2) void attn(
    const bf16* __restrict__ Q, const bf16* __restrict__ Kq,
    const bf16* __restrict__ VT, bf16* __restrict__ O) {
  __shared__ alignas(16) bf16 sK[2][128 * 64];
  __shared__ alignas(16) bf16 sV[2][64 * 128];   // V^T tile: [dh][seq]
  __shared__ alignas(16) bf16 sP[4][32 * 64];    // per-wave P half (32 q x 64 kv), swizzled
  const int tid = threadIdx.x, wave = tid >> 6, lane = tid & 63;
  const int quad = lane >> 4, l16 = lane & 15;
  const int hb = blockIdx.x, qt = blockIdx.y;
  const int h = hb & 15, b = hb >> 4;

  const bf16* Qg = Q + (size_t)(b * SQ + qt * 128) * DM + h * DH;
  const bf16* Kg = Kq + (size_t)(b * SQ) * DM + h * DH;
  const bf16* Vg = VT + (size_t)(h * DH) * MTOT + b * SQ;

  const int srow = lane >> 3, scol = ((lane & 7) ^ srow) * 8;   // 64-wide rows, swizzled
  const int vrow = lane >> 4;                                   // 128-wide rows

  auto stageKV = [&](int t, int buf) {
#pragma unroll
    for (int i = 0; i < 4; i++) {
      const int r = (wave * 4 + i) * 8;
      gld_lds16(Kg + (size_t)(t * 128 + r + srow) * DM + scol, &sK[buf][r * 64]);
    }
#pragma unroll
    for (int i = 0; i < 4; i++) {
      const int r = (wave * 4 + i) * 4;  // 4 VT-rows per wave-load
      const int vchunk = (lane & 15) ^ ((r + vrow) & 7);  // swizzled global chunk
      gld_lds16(Vg + (size_t)(r + vrow) * MTOT + t * 128 + vchunk * 8, &sV[buf][r * 128]);
    }
  };

  // Q fragments in registers: q-row = wave*32 + mt*16 + l16, k = kkh*32 + quad*8 + j
  bf16x8 qF[2][2];
#pragma unroll
  for (int mt = 0; mt < 2; mt++)
#pragma unroll
    for (int kkh = 0; kkh < 2; kkh++)
      qF[mt][kkh] = *(const bf16x8*)(Qg + (size_t)(wave * 32 + mt * 16 + l16) * DM +
                                     kkh * 32 + quad * 8);

  float l_i[2] = {0.f, 0.f};   // per-lane partial row-sums for q = mt*16+l16
  f32x4 o_acc[2][4];
#pragma unroll
  for (int mt = 0; mt < 2; mt++)
#pragma unroll
    for (int n2 = 0; n2 < 4; n2++) o_acc[mt][n2] = (f32x4){0.f, 0.f, 0.f, 0.f};

  stageKV(0, 0);
  for (int t = 0; t < 16; ++t) {
    __syncthreads();  // drains loads issued at t-1 (full compute phase in flight)
    if (t + 1 < 16) stageKV(t + 1, (t + 1) & 1);
    const bf16* cK = sK[t & 1];
    const bf16* cV = sV[t & 1];

    // S^T = K Q^T: block (nt=kv, mt=q); lane holds S[kv=nt*16+quad*4+r][q=mt*16+l16]
    f32x4 sacc[2][8];
#pragma unroll
    for (int mt = 0; mt < 2; mt++)
#pragma unroll
      for (int nt = 0; nt < 8; nt++) sacc[mt][nt] = (f32x4){0.f, 0.f, 0.f, 0.f};
#pragma unroll
    for (int kk = 0; kk < 64; kk += 32) {
      bf16x8 kF[8];
      const int slot = (((kk >> 3) + quad) ^ (l16 & 7)) << 3;
#pragma unroll
      for (int nt = 0; nt < 8; nt++)
        kF[nt] = *(const bf16x8*)&cK[(nt * 16 + l16) * 64 + slot];
#pragma unroll
      for (int mt = 0; mt < 2; mt++)
#pragma unroll
        for (int nt = 0; nt < 8; nt++)
          sacc[mt][nt] = __builtin_amdgcn_mfma_f32_16x16x32_bf16(kF[nt], qF[mt][kk >> 5],
                                                                 sacc[mt][nt], 0, 0, 0);
    }

    // exp2 + packed P store + PV, two kv-halves of 64 through per-wave sP.
    // Same-wave LDS ordering via lgkmcnt; no barrier needed.
#pragma unroll
    for (int half = 0; half < 2; half++) {
#pragma unroll
      for (int mt = 0; mt < 2; mt++) {
        const int row = mt * 16 + l16;
#pragma unroll
        for (int nt4 = 0; nt4 < 4; nt4++) {
          const f32x4 s = sacc[mt][half * 4 + nt4];
          bf16x4 pk;
#pragma unroll
          for (int r = 0; r < 4; r++) {
            const float p = __builtin_amdgcn_exp2f(s[r]);
            l_i[mt] += p;
            pk[r] = (bf16)p;
          }
          // kv_in_half = nt4*16 + quad*4 -> 16B chunk c = 2*nt4 + (quad>>1), 8B sub = quad&1
          const int c = 2 * nt4 + (quad >> 1);
          *(bf16x4*)&sP[wave][row * 64 + ((c ^ (row & 7)) << 3) + (quad & 1) * 4] = pk;
        }
      }
#pragma unroll
      for (int kk = 0; kk < 64; kk += 32) {
        bf16x8 pF[2], vF[4];
#pragma unroll
        for (int mt = 0; mt < 2; mt++) {
          const int row = mt * 16 + l16;
          const int c = (kk >> 3) + quad;
          pF[mt] = *(const bf16x8*)&sP[wave][row * 64 + ((c ^ (row & 7)) << 3)];
        }
#pragma unroll
        for (int n2 = 0; n2 < 4; n2++) {
          const int ch = ((half * 64 + kk) >> 3) + quad;  // logical chunk 0..15
          vF[n2] = *(const bf16x8*)&cV[(n2 * 16 + l16) * 128 + ((ch ^ (l16 & 7)) << 3)];
        }
#pragma unroll
        for (int mt = 0; mt < 2; mt++)
#pragma unroll
          for (int n2 = 0; n2 < 4; n2++)
            o_acc[mt][n2] = __builtin_amdgcn_mfma_f32_16x16x32_bf16(pF[mt], vF[n2],
                                                                    o_acc[mt][n2], 0, 0, 0);
      }
    }
  }

  // l_i lives in S^T space (q = mt*16+l16); o_acc lives in O space (q = mt*16+quad*4+r).
  // Reduce across quads, stash 32 floats in (this wave's) sP, re-read broadcast.
  float* lbuf = (float*)&sP[wave][0];
#pragma unroll
  for (int mt = 0; mt < 2; mt++) {
    float v = l_i[mt];
    v += __shfl_xor(v, 16);
    v += __shfl_xor(v, 32);
    if (quad == 0) lbuf[mt * 16 + l16] = v;
  }
  __builtin_amdgcn_s_waitcnt(0);  // ensure own-wave ds_write visible to own-wave reads
#pragma unroll
  for (int mt = 0; mt < 2; mt++) {
    const f32x4 lv = *(const f32x4*)&lbuf[mt * 16 + quad * 4];
#pragma unroll
    for (int r = 0; r < 4; r++) {
      const float inv = 1.0f / lv[r];
      const int row = qt * 128 + wave * 32 + mt * 16 + quad * 4 + r;
#pragma unroll
      for (int n2 = 0; n2 < 4; n2++) {
        const int col = n2 * 16 + l16;
        O[(size_t)(b * SQ + row) * DM + h * DH + col] = (bf16)(o_acc[mt][n2][r] * inv);
      }
    }
  }
}

extern "C" void kernel_launch(void* const* d_in, const int* in_sizes, int n_in,
                              void* d_out, int out_size, void* d_ws, size_t ws_size,
                              hipStream_t stream) {
  // Reference dtypes: ALL inputs float32, output float32. Internal compute bf16.
  const float* x  = (const float*)d_in[0];
  const float* Wq = (const float*)d_in[1];
  const float* bq = (const float*)d_in[2];
  const float* Wk = (const float*)d_in[3];
  const float* bk = (const float*)d_in[4];
  const float* Wv = (const float*)d_in[5];
  const float* bv = (const float*)d_in[6];
  const float* Wo = (const float*)d_in[7];
  const float* bo = (const float*)d_in[8];
  float* out = (float*)d_out;

  bf16* ws   = (bf16*)d_ws;
  bf16* xb   = ws;                          // [4096][1024]
  bf16* Wqb  = ws + (size_t)MTOT * DM;
  bf16* Wkb  = Wqb + (size_t)DM * DM;
  bf16* Wvb  = Wkb + (size_t)DM * DM;
  bf16* Wob  = Wvb + (size_t)DM * DM;
  bf16* Qw   = Wob + (size_t)DM * DM;       // [4096][1024]  (pre-scaled by QSCALE)
  bf16* Kw   = Qw + (size_t)MTOT * DM;      // [4096][1024]
  bf16* VTw  = Kw + (size_t)MTOT * DM;      // [1024][4096]  (V transposed)
  bf16* Cw   = VTw + (size_t)MTOT * DM;     // [4096][1024]  (context)

  const dim3 blk(256);
  cvt5<<<dim3(MTOT * DM / 1024, 5), blk, 0, stream>>>(Wq, Wk, Wv, Wo, x,
                                                      Wqb, Wkb, Wvb, Wob, xb);
  qkv_fused<<<dim3(32, 8), blk, 0, stream>>>(xb, Wqb, Wkb, Wvb, bq, bk, bv, Qw, Kw, VTw);
  attn<<<dim3(NH * NB, SQ / 128), blk, 0, stream>>>(Qw, Kw, VTw, Cw);
  out_gemm<<<dim3(MTOT / 64, DM / 128), blk, 0, stream>>>(Cw, Wob, bo, out);
}

// Round 10
// 184.720 us; speedup vs baseline: 1.0742x; 1.0742x over previous
//
#include <hip/hip_runtime.h>
#include <hip/hip_bf16.h>

typedef __bf16 bf16;
typedef __bf16 bf16x8 __attribute__((ext_vector_type(8)));
typedef __bf16 bf16x4 __attribute__((ext_vector_type(4)));
typedef float f32x4 __attribute__((ext_vector_type(4)));

constexpr int DM = 1024, NH = 16, DH = 64, NB = 2, SQ = 2048;
constexpr int MTOT = NB * SQ;  // 4096
// Q is pre-scaled by 1/sqrt(DH) * log2(e) so attn does bare exp2(S).
constexpr float QSCALE = 0.125f * 1.44269504088896f;

// async global->LDS, 16B per lane; LDS dest is wave-uniform base + lane*16 (HW rule)
__device__ __forceinline__ void gld_lds16(const bf16* g, bf16* l) {
  __builtin_amdgcn_global_load_lds(
      (const __attribute__((address_space(1))) void*)g,
      (__attribute__((address_space(3))) void*)l, 16, 0, 0);
}

// ============ fp32 -> bf16 conversion: 4x W (1M elts each) + x (4M elts) ============
// Exact grid: (1024, 5); y<4 -> one 1M weight, y==4 -> x (4M) via 4-step loop.
__global__ __launch_bounds__(256) void cvt5(
    const float* __restrict__ s0, const float* __restrict__ s1,
    const float* __restrict__ s2, const float* __restrict__ s3,
    const float* __restrict__ s4,
    bf16* __restrict__ d0, bf16* __restrict__ d1, bf16* __restrict__ d2,
    bf16* __restrict__ d3, bf16* __restrict__ d4) {
  const int idx = (blockIdx.x * 256 + threadIdx.x) * 4;
  const float* src; bf16* dst; int reps;
  switch (blockIdx.y) {
    case 0: src = s0; dst = d0; reps = 1; break;
    case 1: src = s1; dst = d1; reps = 1; break;
    case 2: src = s2; dst = d2; reps = 1; break;
    case 3: src = s3; dst = d3; reps = 1; break;
    default: src = s4; dst = d4; reps = 4; break;
  }
  for (int j = 0; j < reps; j++) {
    const int o = idx + j * (DM * DM);
    const float4 v = *(const float4*)(src + o);
    *(bf16x4*)(dst + o) = (bf16x4){(bf16)v.x, (bf16)v.y, (bf16)v.z, (bf16)v.w};
  }
}

// ======== GEMM-NT tile body: C[M][N] = (A[M][K] * B[N][K]^T + bias) * cscale ========
// BM x 128 tile, BK=64, 256 threads (4 waves). BM=128: wave -> 64x64; BM=64: wave -> 64x32.
// Single-buffered 2-barrier K-loop, 32/24 KB LDS -> 3+ blocks/CU with launch_bounds(256,4):
// TLP across blocks hides the staging latency (measured better than dbuf at 2/CU, R7;
// and better than high-ratio mega-tiles at 1/CU, R9). LDS XOR-swizzled: 16B-chunk c of
// row r at slot c^(r&7) -> ds_read_b128 conflict-free.
template <int BM, typename OutT>
__device__ __forceinline__ void gemm_tile(
    const bf16* __restrict__ A, const bf16* __restrict__ Bm,
    const float* __restrict__ bias, OutT* __restrict__ C,
    int rowA0, int rowB0, int N, int K, bool bias_row, float cscale,
    bf16* sA, bf16* sB) {
  constexpr int NT = (BM == 128) ? 4 : 2;
  const int tid = threadIdx.x;
  const int wave = tid >> 6, lane = tid & 63;
  const int quad = lane >> 4, l16 = lane & 15;
  const int row0w = (BM == 128) ? (wave >> 1) * 64 : 0;
  const int col0w = (BM == 128) ? (wave & 1) * 64 : wave * 32;

  f32x4 acc[4][NT];
#pragma unroll
  for (int i = 0; i < 4; i++)
#pragma unroll
    for (int j = 0; j < NT; j++) acc[i][j] = (f32x4){0.f, 0.f, 0.f, 0.f};

  const int srow = lane >> 3;                         // 0..7
  const int scol = ((lane & 7) ^ srow) * 8;           // swizzled global chunk

  for (int kt = 0; kt < K; kt += 64) {
#pragma unroll
    for (int i = 0; i < BM / 32; i++) {
      const int r = i * 32 + wave * 8;
      gld_lds16(A + (size_t)(rowA0 + r + srow) * K + kt + scol, &sA[r * 64]);
    }
#pragma unroll
    for (int i = 0; i < 4; i++) {
      const int r = i * 32 + wave * 8;
      gld_lds16(Bm + (size_t)(rowB0 + r + srow) * K + kt + scol, &sB[r * 64]);
    }
    __syncthreads();  // drains vmcnt for global_load_lds
#pragma unroll
    for (int kk = 0; kk < 64; kk += 32) {
      bf16x8 aF[4], bF[NT];
      const int slot = (((kk >> 3) + quad) ^ (l16 & 7)) << 3;
#pragma unroll
      for (int mt = 0; mt < 4; mt++)
        aF[mt] = *(const bf16x8*)&sA[(row0w + mt * 16 + l16) * 64 + slot];
#pragma unroll
      for (int nt = 0; nt < NT; nt++)
        bF[nt] = *(const bf16x8*)&sB[(col0w + nt * 16 + l16) * 64 + slot];
#pragma unroll
      for (int mt = 0; mt < 4; mt++)
#pragma unroll
        for (int nt = 0; nt < NT; nt++)
          acc[mt][nt] = __builtin_amdgcn_mfma_f32_16x16x32_bf16(aF[mt], bF[nt], acc[mt][nt], 0, 0, 0);
    }
    __syncthreads();
  }

  // epilogue: C/D layout col=lane&15, row=quad*4+reg (verified m89/m91)
#pragma unroll
  for (int mt = 0; mt < 4; mt++) {
#pragma unroll
    for (int nt = 0; nt < NT; nt++) {
#pragma unroll
      for (int r = 0; r < 4; r++) {
        const int row = rowA0 + row0w + mt * 16 + quad * 4 + r;
        const int col = rowB0 + col0w + nt * 16 + l16;
        const float bb = bias_row ? bias[row] : bias[col];
        C[(size_t)row * N + col] = (OutT)((acc[mt][nt][r] + bb) * cscale);
      }
    }
  }
}

// Fused Q/K/V^T projection: grid (32, 8, 3). z=0 -> Q (pre-scaled), z=1 -> K, z=2 -> V^T.
// 768 blocks, 32 KB LDS, VGPR<=128 -> 3 blocks/CU (all co-resident). [R8: best measured]
__global__ __launch_bounds__(256, 4) void qkv_gemm(
    const bf16* __restrict__ xb, const bf16* __restrict__ Wqb,
    const bf16* __restrict__ Wkb, const bf16* __restrict__ Wvb,
    const float* __restrict__ bq, const float* __restrict__ bk,
    const float* __restrict__ bv,
    bf16* __restrict__ Qw, bf16* __restrict__ Kw, bf16* __restrict__ VTw) {
  __shared__ alignas(16) bf16 sA[128 * 64];
  __shared__ alignas(16) bf16 sB[128 * 64];
  if (blockIdx.z == 0) {
    gemm_tile<128, bf16>(xb, Wqb, bq, Qw, blockIdx.x * 128, blockIdx.y * 128, DM, DM, false, QSCALE, sA, sB);
  } else if (blockIdx.z == 1) {
    gemm_tile<128, bf16>(xb, Wkb, bk, Kw, blockIdx.x * 128, blockIdx.y * 128, DM, DM, false, 1.0f, sA, sB);
  } else {
    // VT[n][m] = sum_k Wv[n][k] x[m][k] + bv[n]  (swapped operands -> V^T layout directly)
    const int id = blockIdx.y * 32 + blockIdx.x;  // 0..255
    gemm_tile<128, bf16>(Wvb, xb, bv, VTw, (id >> 5) * 128, (id & 31) * 128, MTOT, DM, true, 1.0f, sA, sB);
  }
}

// Output projection: BM=64 tiles -> grid (64, 8) = 512 blocks -> 2 blocks/CU.
__global__ __launch_bounds__(256, 4) void out_gemm(
    const bf16* __restrict__ A, const bf16* __restrict__ Bm,
    const float* __restrict__ bias, float* __restrict__ C) {
  __shared__ alignas(16) bf16 sA[64 * 64];
  __shared__ alignas(16) bf16 sB[128 * 64];
  gemm_tile<64, float>(A, Bm, bias, C, blockIdx.x * 64, blockIdx.y * 128, DM, DM, false, 1.0f, sA, sB);
}

// ================= Flash attention (no-max softmax, S^T orientation) =================
// grid: (hb=32, qt=16); linear block id ≡ hb (mod 8) -> all 16 qt-blocks of one (b,h)
// share an XCD (K/V stay L2-resident). Q tile 128x64 in REGISTERS. 16 KV tiles of 128,
// double-buffered, 1 barrier/tile. S^T = K*Q^T (operand swap): lane holds 4 contiguous
// kv -> packed b64 P-stores, per-lane scalar l accumulation (l-via-MFMA measured SLOWER
// in R8). sK/sV/sP XOR-swizzled at 16B granularity. LDS = 80 KB -> 2 blocks/CU (= grid cap).
__global__ __launch_bounds__(256, 2) void attn(
    const bf16* __restrict__ Q, const bf16* __restrict__ Kq,
    const bf16* __restrict__ VT, bf16* __restrict__ O) {
  __shared__ alignas(16) bf16 sK[2][128 * 64];
  __shared__ alignas(16) bf16 sV[2][64 * 128];   // V^T tile: [dh][seq]
  __shared__ alignas(16) bf16 sP[4][32 * 64];    // per-wave P half (32 q x 64 kv), swizzled
  const int tid = threadIdx.x, wave = tid >> 6, lane = tid & 63;
  const int quad = lane >> 4, l16 = lane & 15;
  const int hb = blockIdx.x, qt = blockIdx.y;
  const int h = hb & 15, b = hb >> 4;

  const bf16* Qg = Q + (size_t)(b * SQ + qt * 128) * DM + h * DH;
  const bf16* Kg = Kq + (size_t)(b * SQ) * DM + h * DH;
  const bf16* Vg = VT + (size_t)(h * DH) * MTOT + b * SQ;

  const int srow = lane >> 3, scol = ((lane & 7) ^ srow) * 8;   // 64-wide rows, swizzled
  const int vrow = lane >> 4;                                   // 128-wide rows

  auto stageKV = [&](int t, int buf) {
#pragma unroll
    for (int i = 0; i < 4; i++) {
      const int r = (wave * 4 + i) * 8;
      gld_lds16(Kg + (size_t)(t * 128 + r + srow) * DM + scol, &sK[buf][r * 64]);
    }
#pragma unroll
    for (int i = 0; i < 4; i++) {
      const int r = (wave * 4 + i) * 4;  // 4 VT-rows per wave-load
      const int vchunk = (lane & 15) ^ ((r + vrow) & 7);  // swizzled global chunk
      gld_lds16(Vg + (size_t)(r + vrow) * MTOT + t * 128 + vchunk * 8, &sV[buf][r * 128]);
    }
  };

  // Q fragments in registers: q-row = wave*32 + mt*16 + l16, k = kkh*32 + quad*8 + j
  bf16x8 qF[2][2];
#pragma unroll
  for (int mt = 0; mt < 2; mt++)
#pragma unroll
    for (int kkh = 0; kkh < 2; kkh++)
      qF[mt][kkh] = *(const bf16x8*)(Qg + (size_t)(wave * 32 + mt * 16 + l16) * DM +
                                     kkh * 32 + quad * 8);

  float l_i[2] = {0.f, 0.f};   // per-lane partial row-sums for q = mt*16+l16
  f32x4 o_acc[2][4];
#pragma unroll
  for (int mt = 0; mt < 2; mt++)
#pragma unroll
    for (int n2 = 0; n2 < 4; n2++) o_acc[mt][n2] = (f32x4){0.f, 0.f, 0.f, 0.f};

  stageKV(0, 0);
  for (int t = 0; t < 16; ++t) {
    __syncthreads();  // drains loads issued at t-1 (full compute phase in flight)
    if (t + 1 < 16) stageKV(t + 1, (t + 1) & 1);
    const bf16* cK = sK[t & 1];
    const bf16* cV = sV[t & 1];

    // S^T = K Q^T: block (nt=kv, mt=q); lane holds S[kv=nt*16+quad*4+r][q=mt*16+l16]
    f32x4 sacc[2][8];
#pragma unroll
    for (int mt = 0; mt < 2; mt++)
#pragma unroll
      for (int nt = 0; nt < 8; nt++) sacc[mt][nt] = (f32x4){0.f, 0.f, 0.f, 0.f};
#pragma unroll
    for (int kk = 0; kk < 64; kk += 32) {
      bf16x8 kF[8];
      const int slot = (((kk >> 3) + quad) ^ (l16 & 7)) << 3;
#pragma unroll
      for (int nt = 0; nt < 8; nt++)
        kF[nt] = *(const bf16x8*)&cK[(nt * 16 + l16) * 64 + slot];
#pragma unroll
      for (int mt = 0; mt < 2; mt++)
#pragma unroll
        for (int nt = 0; nt < 8; nt++)
          sacc[mt][nt] = __builtin_amdgcn_mfma_f32_16x16x32_bf16(kF[nt], qF[mt][kk >> 5],
                                                                 sacc[mt][nt], 0, 0, 0);
    }

    // exp2 + packed P store + PV, two kv-halves of 64 through per-wave sP.
    // Same-wave LDS ordering via lgkmcnt; no barrier needed.
#pragma unroll
    for (int half = 0; half < 2; half++) {
#pragma unroll
      for (int mt = 0; mt < 2; mt++) {
        const int row = mt * 16 + l16;
#pragma unroll
        for (int nt4 = 0; nt4 < 4; nt4++) {
          const f32x4 s = sacc[mt][half * 4 + nt4];
          bf16x4 pk;
#pragma unroll
          for (int r = 0; r < 4; r++) {
            const float p = __builtin_amdgcn_exp2f(s[r]);
            l_i[mt] += p;
            pk[r] = (bf16)p;
          }
          // kv_in_half = nt4*16 + quad*4 -> 16B chunk c = 2*nt4 + (quad>>1), 8B sub = quad&1
          const int c = 2 * nt4 + (quad >> 1);
          *(bf16x4*)&sP[wave][row * 64 + ((c ^ (row & 7)) << 3) + (quad & 1) * 4] = pk;
        }
      }
#pragma unroll
      for (int kk = 0; kk < 64; kk += 32) {
        bf16x8 pF[2], vF[4];
#pragma unroll
        for (int mt = 0; mt < 2; mt++) {
          const int row = mt * 16 + l16;
          const int c = (kk >> 3) + quad;
          pF[mt] = *(const bf16x8*)&sP[wave][row * 64 + ((c ^ (row & 7)) << 3)];
        }
#pragma unroll
        for (int n2 = 0; n2 < 4; n2++) {
          const int ch = ((half * 64 + kk) >> 3) + quad;  // logical chunk 0..15
          vF[n2] = *(const bf16x8*)&cV[(n2 * 16 + l16) * 128 + ((ch ^ (l16 & 7)) << 3)];
        }
#pragma unroll
        for (int mt = 0; mt < 2; mt++)
#pragma unroll
          for (int n2 = 0; n2 < 4; n2++)
            o_acc[mt][n2] = __builtin_amdgcn_mfma_f32_16x16x32_bf16(pF[mt], vF[n2],
                                                                    o_acc[mt][n2], 0, 0, 0);
      }
    }
  }

  // l_i lives in S^T space (q = mt*16+l16); o_acc lives in O space (q = mt*16+quad*4+r).
  // Reduce across quads, stash 32 floats in (this wave's) sP, re-read broadcast.
  float* lbuf = (float*)&sP[wave][0];
#pragma unroll
  for (int mt = 0; mt < 2; mt++) {
    float v = l_i[mt];
    v += __shfl_xor(v, 16);
    v += __shfl_xor(v, 32);
    if (quad == 0) lbuf[mt * 16 + l16] = v;
  }
  __builtin_amdgcn_s_waitcnt(0);  // ensure own-wave ds_write visible to own-wave reads
#pragma unroll
  for (int mt = 0; mt < 2; mt++) {
    const f32x4 lv = *(const f32x4*)&lbuf[mt * 16 + quad * 4];
#pragma unroll
    for (int r = 0; r < 4; r++) {
      const float inv = 1.0f / lv[r];
      const int row = qt * 128 + wave * 32 + mt * 16 + quad * 4 + r;
#pragma unroll
      for (int n2 = 0; n2 < 4; n2++) {
        const int col = n2 * 16 + l16;
        O[(size_t)(b * SQ + row) * DM + h * DH + col] = (bf16)(o_acc[mt][n2][r] * inv);
      }
    }
  }
}

extern "C" void kernel_launch(void* const* d_in, const int* in_sizes, int n_in,
                              void* d_out, int out_size, void* d_ws, size_t ws_size,
                              hipStream_t stream) {
  // Reference dtypes: ALL inputs float32, output float32. Internal compute bf16.
  const float* x  = (const float*)d_in[0];
  const float* Wq = (const float*)d_in[1];
  const float* bq = (const float*)d_in[2];
  const float* Wk = (const float*)d_in[3];
  const float* bk = (const float*)d_in[4];
  const float* Wv = (const float*)d_in[5];
  const float* bv = (const float*)d_in[6];
  const float* Wo = (const float*)d_in[7];
  const float* bo = (const float*)d_in[8];
  float* out = (float*)d_out;

  bf16* ws   = (bf16*)d_ws;
  bf16* xb   = ws;                          // [4096][1024]
  bf16* Wqb  = ws + (size_t)MTOT * DM;
  bf16* Wkb  = Wqb + (size_t)DM * DM;
  bf16* Wvb  = Wkb + (size_t)DM * DM;
  bf16* Wob  = Wvb + (size_t)DM * DM;
  bf16* Qw   = Wob + (size_t)DM * DM;       // [4096][1024]  (pre-scaled by QSCALE)
  bf16* Kw   = Qw + (size_t)MTOT * DM;      // [4096][1024]
  bf16* VTw  = Kw + (size_t)MTOT * DM;      // [1024][4096]  (V transposed)
  bf16* Cw   = VTw + (size_t)MTOT * DM;     // [4096][1024]  (context)

  const dim3 blk(256);
  cvt5<<<dim3(1024, 5), blk, 0, stream>>>(Wq, Wk, Wv, Wo, x,
                                          Wqb, Wkb, Wvb, Wob, xb);
  qkv_gemm<<<dim3(32, 8, 3), blk, 0, stream>>>(xb, Wqb, Wkb, Wvb, bq, bk, bv, Qw, Kw, VTw);
  attn<<<dim3(NH * NB, SQ / 128), blk, 0, stream>>>(Qw, Kw, VTw, Cw);
  out_gemm<<<dim3(MTOT / 64, DM / 128), blk, 0, stream>>>(Cw, Wob, bo, out);
}

// Round 11
// 182.093 us; speedup vs baseline: 1.0897x; 1.0144x over previous
//
#include <hip/hip_runtime.h>
#include <hip/hip_bf16.h>

typedef __bf16 bf16;
typedef __bf16 bf16x8 __attribute__((ext_vector_type(8)));
typedef __bf16 bf16x4 __attribute__((ext_vector_type(4)));
typedef float f32x4 __attribute__((ext_vector_type(4)));

constexpr int DM = 1024, NH = 16, DH = 64, NB = 2, SQ = 2048;
constexpr int MTOT = NB * SQ;  // 4096
// Q is pre-scaled by 1/sqrt(DH) * log2(e) so attn does bare exp2(S).
constexpr float QSCALE = 0.125f * 1.44269504088896f;

// async global->LDS, 16B per lane; LDS dest is wave-uniform base + lane*16 (HW rule)
__device__ __forceinline__ void gld_lds16(const bf16* g, bf16* l) {
  __builtin_amdgcn_global_load_lds(
      (const __attribute__((address_space(1))) void*)g,
      (__attribute__((address_space(3))) void*)l, 16, 0, 0);
}

// ============ fp32 -> bf16 conversion: 4x W (1M elts each) + x (4M elts) ============
// Flat grid (1024, 8): y<4 -> weight y; y>=4 -> quarter y-4 of x. Every block full;
// one independent load/store per thread (runtime-reps loop was 10 us SLOWER - R10).
__global__ __launch_bounds__(256) void cvt5(
    const float* __restrict__ s0, const float* __restrict__ s1,
    const float* __restrict__ s2, const float* __restrict__ s3,
    const float* __restrict__ s4,
    bf16* __restrict__ d0, bf16* __restrict__ d1, bf16* __restrict__ d2,
    bf16* __restrict__ d3, bf16* __restrict__ d4) {
  const int idx = (blockIdx.x * 256 + threadIdx.x) * 4;
  const float* src; bf16* dst;
  switch (blockIdx.y) {
    case 0: src = s0; dst = d0; break;
    case 1: src = s1; dst = d1; break;
    case 2: src = s2; dst = d2; break;
    case 3: src = s3; dst = d3; break;
    default: {
      const int off = (blockIdx.y - 4) * (DM * DM);
      src = s4 + off; dst = d4 + off; break;
    }
  }
  const float4 v = *(const float4*)(src + idx);
  *(bf16x4*)(dst + idx) = (bf16x4){(bf16)v.x, (bf16)v.y, (bf16)v.z, (bf16)v.w};
}

// ======== GEMM-NT tile body: C[M][N] = (A[M][K] * B[N][K]^T + bias) * cscale ========
// BM x 128 tile, BK=64, 256 threads (4 waves). BM=128: wave -> 64x64; BM=64: wave -> 64x32.
// Single-buffered 2-barrier K-loop, 32/24 KB LDS -> 3+ blocks/CU with launch_bounds(256,4):
// TLP across blocks hides staging latency (beats dbuf@2/CU [R7] and mega-tile@1/CU [R9]).
// LDS XOR-swizzled: 16B-chunk c of row r at slot c^(r&7) -> ds_read_b128 conflict-free.
template <int BM, typename OutT>
__device__ __forceinline__ void gemm_tile(
    const bf16* __restrict__ A, const bf16* __restrict__ Bm,
    const float* __restrict__ bias, OutT* __restrict__ C,
    int rowA0, int rowB0, int N, int K, bool bias_row, float cscale,
    bf16* sA, bf16* sB) {
  constexpr int NT = (BM == 128) ? 4 : 2;
  const int tid = threadIdx.x;
  const int wave = tid >> 6, lane = tid & 63;
  const int quad = lane >> 4, l16 = lane & 15;
  const int row0w = (BM == 128) ? (wave >> 1) * 64 : 0;
  const int col0w = (BM == 128) ? (wave & 1) * 64 : wave * 32;

  f32x4 acc[4][NT];
#pragma unroll
  for (int i = 0; i < 4; i++)
#pragma unroll
    for (int j = 0; j < NT; j++) acc[i][j] = (f32x4){0.f, 0.f, 0.f, 0.f};

  const int srow = lane >> 3;                         // 0..7
  const int scol = ((lane & 7) ^ srow) * 8;           // swizzled global chunk

  for (int kt = 0; kt < K; kt += 64) {
#pragma unroll
    for (int i = 0; i < BM / 32; i++) {
      const int r = i * 32 + wave * 8;
      gld_lds16(A + (size_t)(rowA0 + r + srow) * K + kt + scol, &sA[r * 64]);
    }
#pragma unroll
    for (int i = 0; i < 4; i++) {
      const int r = i * 32 + wave * 8;
      gld_lds16(Bm + (size_t)(rowB0 + r + srow) * K + kt + scol, &sB[r * 64]);
    }
    __syncthreads();  // drains vmcnt for global_load_lds
#pragma unroll
    for (int kk = 0; kk < 64; kk += 32) {
      bf16x8 aF[4], bF[NT];
      const int slot = (((kk >> 3) + quad) ^ (l16 & 7)) << 3;
#pragma unroll
      for (int mt = 0; mt < 4; mt++)
        aF[mt] = *(const bf16x8*)&sA[(row0w + mt * 16 + l16) * 64 + slot];
#pragma unroll
      for (int nt = 0; nt < NT; nt++)
        bF[nt] = *(const bf16x8*)&sB[(col0w + nt * 16 + l16) * 64 + slot];
#pragma unroll
      for (int mt = 0; mt < 4; mt++)
#pragma unroll
        for (int nt = 0; nt < NT; nt++)
          acc[mt][nt] = __builtin_amdgcn_mfma_f32_16x16x32_bf16(aF[mt], bF[nt], acc[mt][nt], 0, 0, 0);
    }
    __syncthreads();
  }

  // epilogue: C/D layout col=lane&15, row=quad*4+reg (verified m89/m91)
#pragma unroll
  for (int mt = 0; mt < 4; mt++) {
#pragma unroll
    for (int nt = 0; nt < NT; nt++) {
#pragma unroll
      for (int r = 0; r < 4; r++) {
        const int row = rowA0 + row0w + mt * 16 + quad * 4 + r;
        const int col = rowB0 + col0w + nt * 16 + l16;
        const float bb = bias_row ? bias[row] : bias[col];
        C[(size_t)row * N + col] = (OutT)((acc[mt][nt][r] + bb) * cscale);
      }
    }
  }
}

// Fused Q/K/V^T projection: grid (32, 8, 3). z=0 -> Q (pre-scaled), z=1 -> K, z=2 -> V^T.
// 768 blocks, 32 KB LDS, VGPR<=128 -> 3 blocks/CU (all co-resident). [R8: best measured]
__global__ __launch_bounds__(256, 4) void qkv_gemm(
    const bf16* __restrict__ xb, const bf16* __restrict__ Wqb,
    const bf16* __restrict__ Wkb, const bf16* __restrict__ Wvb,
    const float* __restrict__ bq, const float* __restrict__ bk,
    const float* __restrict__ bv,
    bf16* __restrict__ Qw, bf16* __restrict__ Kw, bf16* __restrict__ VTw) {
  __shared__ alignas(16) bf16 sA[128 * 64];
  __shared__ alignas(16) bf16 sB[128 * 64];
  if (blockIdx.z == 0) {
    gemm_tile<128, bf16>(xb, Wqb, bq, Qw, blockIdx.x * 128, blockIdx.y * 128, DM, DM, false, QSCALE, sA, sB);
  } else if (blockIdx.z == 1) {
    gemm_tile<128, bf16>(xb, Wkb, bk, Kw, blockIdx.x * 128, blockIdx.y * 128, DM, DM, false, 1.0f, sA, sB);
  } else {
    // VT[n][m] = sum_k Wv[n][k] x[m][k] + bv[n]  (swapped operands -> V^T layout directly)
    const int id = blockIdx.y * 32 + blockIdx.x;  // 0..255
    gemm_tile<128, bf16>(Wvb, xb, bv, VTw, (id >> 5) * 128, (id & 31) * 128, MTOT, DM, true, 1.0f, sA, sB);
  }
}

// Output projection: BM=64 tiles -> grid (64, 8) = 512 blocks -> 2 blocks/CU.
__global__ __launch_bounds__(256, 4) void out_gemm(
    const bf16* __restrict__ A, const bf16* __restrict__ Bm,
    const float* __restrict__ bias, float* __restrict__ C) {
  __shared__ alignas(16) bf16 sA[64 * 64];
  __shared__ alignas(16) bf16 sB[128 * 64];
  gemm_tile<64, float>(A, Bm, bias, C, blockIdx.x * 64, blockIdx.y * 128, DM, DM, false, 1.0f, sA, sB);
}

// ================= Flash attention (no-max softmax, S^T, 2x2 wave split) =================
// grid: (hb=32, qt=16); linear block id ≡ hb (mod 8) -> XCD-local K/V (L2-resident).
// Waves split 2x2: qg = wave>>1 owns 64 q, kg = wave&1 owns 64 kv of each 128-kv tile.
// This doubles per-read MFMA amortization: per tile per wave only 8 kF + 8 vF + 8 pF
// b128 reads (was 16+16+8 with the 32qx128kv wave-tile - LDS pipe was 53% busy, the
// binding resource). Q (64x64) in REGISTERS. K/V double-buffered, 1 barrier/tile.
// S^T = K*Q^T: lane holds 4 contiguous kv -> packed b64 P-stores; l accumulates
// per-lane (q=l16). kg-pair o/l reduced once at end through LDS (reuses sK).
// sK/sV/sP XOR-swizzled at 16B granularity. LDS = 80 KB -> 2 blocks/CU (= grid cap).
__global__ __launch_bounds__(256, 2) void attn(
    const bf16* __restrict__ Q, const bf16* __restrict__ Kq,
    const bf16* __restrict__ VT, bf16* __restrict__ O) {
  __shared__ alignas(16) bf16 sK[2][128 * 64];
  __shared__ alignas(16) bf16 sV[2][64 * 128];   // V^T tile: [dh][seq]
  __shared__ alignas(16) bf16 sP[4][64 * 32];    // per-wave P quarter (64 q x 32 kv), swizzled
  const int tid = threadIdx.x, wave = tid >> 6, lane = tid & 63;
  const int quad = lane >> 4, l16 = lane & 15;
  const int qg = wave >> 1, kg = wave & 1;
  const int hb = blockIdx.x, qt = blockIdx.y;
  const int h = hb & 15, b = hb >> 4;

  const bf16* Qg = Q + (size_t)(b * SQ + qt * 128) * DM + h * DH;
  const bf16* Kg = Kq + (size_t)(b * SQ) * DM + h * DH;
  const bf16* Vg = VT + (size_t)(h * DH) * MTOT + b * SQ;

  const int srow = lane >> 3, scol = ((lane & 7) ^ srow) * 8;   // 64-wide rows, swizzled
  const int vrow = lane >> 4;                                   // 128-wide rows

  auto stageKV = [&](int t, int buf) {
#pragma unroll
    for (int i = 0; i < 4; i++) {
      const int r = (wave * 4 + i) * 8;
      gld_lds16(Kg + (size_t)(t * 128 + r + srow) * DM + scol, &sK[buf][r * 64]);
    }
#pragma unroll
    for (int i = 0; i < 4; i++) {
      const int r = (wave * 4 + i) * 4;  // 4 VT-rows per wave-load
      const int vchunk = (lane & 15) ^ ((r + vrow) & 7);  // swizzled global chunk
      gld_lds16(Vg + (size_t)(r + vrow) * MTOT + t * 128 + vchunk * 8, &sV[buf][r * 128]);
    }
  };

  // Q fragments in registers: q-row = qg*64 + mt*16 + l16, k = kkh*32 + quad*8 + j
  bf16x8 qF[4][2];
#pragma unroll
  for (int mt = 0; mt < 4; mt++)
#pragma unroll
    for (int kkh = 0; kkh < 2; kkh++)
      qF[mt][kkh] = *(const bf16x8*)(Qg + (size_t)(qg * 64 + mt * 16 + l16) * DM +
                                     kkh * 32 + quad * 8);

  float l_i[4] = {0.f, 0.f, 0.f, 0.f};   // per-lane partial row-sums, q = qg*64+mt*16+l16
  f32x4 o_acc[4][4];
#pragma unroll
  for (int mt = 0; mt < 4; mt++)
#pragma unroll
    for (int n2 = 0; n2 < 4; n2++) o_acc[mt][n2] = (f32x4){0.f, 0.f, 0.f, 0.f};

  stageKV(0, 0);
  for (int t = 0; t < 16; ++t) {
    __syncthreads();  // drains loads issued at t-1 (full compute phase in flight)
    if (t + 1 < 16) stageKV(t + 1, (t + 1) & 1);
    const bf16* cK = sK[t & 1];
    const bf16* cV = sV[t & 1];

    // S^T = K Q^T on the wave's 64kv x 64q patch:
    // lane holds S[kv = kg*64 + nt*16 + quad*4 + r][q = qg*64 + mt*16 + l16]
    f32x4 sacc[4][4];  // [nt][mt]
#pragma unroll
    for (int nt = 0; nt < 4; nt++)
#pragma unroll
      for (int mt = 0; mt < 4; mt++) sacc[nt][mt] = (f32x4){0.f, 0.f, 0.f, 0.f};
#pragma unroll
    for (int kk = 0; kk < 64; kk += 32) {
      bf16x8 kF[4];
      const int slot = (((kk >> 3) + quad) ^ (l16 & 7)) << 3;
#pragma unroll
      for (int nt = 0; nt < 4; nt++)
        kF[nt] = *(const bf16x8*)&cK[(kg * 64 + nt * 16 + l16) * 64 + slot];
#pragma unroll
      for (int nt = 0; nt < 4; nt++)
#pragma unroll
        for (int mt = 0; mt < 4; mt++)
          sacc[nt][mt] = __builtin_amdgcn_mfma_f32_16x16x32_bf16(kF[nt], qF[mt][kk >> 5],
                                                                 sacc[nt][mt], 0, 0, 0);
    }

    // exp2 + packed P store + PV, in two kv-quarters of 32 through per-wave sP
    // (same-wave LDS ordering via lgkmcnt; no barrier).
#pragma unroll
    for (int kq = 0; kq < 2; kq++) {
#pragma unroll
      for (int mt = 0; mt < 4; mt++) {
        const int row = mt * 16 + l16;  // q local 0..63; sP row stride 32 bf16
#pragma unroll
        for (int ntl = 0; ntl < 2; ntl++) {
          const f32x4 s = sacc[kq * 2 + ntl][mt];
          bf16x4 pk;
#pragma unroll
          for (int r = 0; r < 4; r++) {
            const float p = __builtin_amdgcn_exp2f(s[r]);
            l_i[mt] += p;
            pk[r] = (bf16)p;
          }
          // kv-in-quarter = ntl*16 + quad*4 -> 16B chunk c = ntl*2 + (quad>>1), 8B sub = quad&1
          const int c = ntl * 2 + (quad >> 1);
          *(bf16x4*)&sP[wave][row * 32 + ((c ^ (row & 3)) << 3) + (quad & 1) * 4] = pk;
        }
      }
      bf16x8 pF[4], vF[4];
#pragma unroll
      for (int mt = 0; mt < 4; mt++) {
        const int row = mt * 16 + l16;
        pF[mt] = *(const bf16x8*)&sP[wave][row * 32 + ((quad ^ (row & 3)) << 3)];
      }
      const int chbase = kg * 8 + kq * 4;  // global 16B-chunk base within 128-kv tile
#pragma unroll
      for (int n2 = 0; n2 < 4; n2++)
        vF[n2] = *(const bf16x8*)&cV[(n2 * 16 + l16) * 128 +
                                     (((chbase + quad) ^ (l16 & 7)) << 3)];
#pragma unroll
      for (int mt = 0; mt < 4; mt++)
#pragma unroll
        for (int n2 = 0; n2 < 4; n2++)
          o_acc[mt][n2] = __builtin_amdgcn_mfma_f32_16x16x32_bf16(pF[mt], vF[n2],
                                                                  o_acc[mt][n2], 0, 0, 0);
    }
  }

  // ---- kg-pair reduction: o and l summed across the two kv-half waves of each qg ----
  __syncthreads();                       // tile loop done; sK/sV reusable
  float* obuf = (float*)&sK[0][0];       // [qg][64 q][64 dh] f32 = 32 KB
  float* lb   = (float*)&sV[0][0];       // [qg*2+kg][64 q] f32
  float lred[4];
#pragma unroll
  for (int mt = 0; mt < 4; mt++) {
    float v = l_i[mt];
    v += __shfl_xor(v, 16);
    v += __shfl_xor(v, 32);
    lred[mt] = v;                        // full kv-half sum for q = mt*16 + l16
  }
  if (quad == 0)
#pragma unroll
    for (int mt = 0; mt < 4; mt++) lb[(qg * 2 + kg) * 64 + mt * 16 + l16] = lred[mt];
  if (kg == 1) {
#pragma unroll
    for (int mt = 0; mt < 4; mt++)
#pragma unroll
      for (int n2 = 0; n2 < 4; n2++)
#pragma unroll
        for (int r = 0; r < 4; r++)
          obuf[qg * 4096 + (mt * 16 + quad * 4 + r) * 64 + n2 * 16 + l16] = o_acc[mt][n2][r];
  }
  __syncthreads();
  if (kg == 0) {
#pragma unroll
    for (int mt = 0; mt < 4; mt++) {
      const f32x4 l0 = *(const f32x4*)&lb[(qg * 2 + 0) * 64 + mt * 16 + quad * 4];
      const f32x4 l1 = *(const f32x4*)&lb[(qg * 2 + 1) * 64 + mt * 16 + quad * 4];
#pragma unroll
      for (int r = 0; r < 4; r++) {
        const float inv = 1.0f / (l0[r] + l1[r]);
        const int row = qt * 128 + qg * 64 + mt * 16 + quad * 4 + r;
#pragma unroll
        for (int n2 = 0; n2 < 4; n2++) {
          const float o = o_acc[mt][n2][r] +
                          obuf[qg * 4096 + (mt * 16 + quad * 4 + r) * 64 + n2 * 16 + l16];
          O[(size_t)(b * SQ + row) * DM + h * DH + n2 * 16 + l16] = (bf16)(o * inv);
        }
      }
    }
  }
}

extern "C" void kernel_launch(void* const* d_in, const int* in_sizes, int n_in,
                              void* d_out, int out_size, void* d_ws, size_t ws_size,
                              hipStream_t stream) {
  // Reference dtypes: ALL inputs float32, output float32. Internal compute bf16.
  const float* x  = (const float*)d_in[0];
  const float* Wq = (const float*)d_in[1];
  const float* bq = (const float*)d_in[2];
  const float* Wk = (const float*)d_in[3];
  const float* bk = (const float*)d_in[4];
  const float* Wv = (const float*)d_in[5];
  const float* bv = (const float*)d_in[6];
  const float* Wo = (const float*)d_in[7];
  const float* bo = (const float*)d_in[8];
  float* out = (float*)d_out;

  bf16* ws   = (bf16*)d_ws;
  bf16* xb   = ws;                          // [4096][1024]
  bf16* Wqb  = ws + (size_t)MTOT * DM;
  bf16* Wkb  = Wqb + (size_t)DM * DM;
  bf16* Wvb  = Wkb + (size_t)DM * DM;
  bf16* Wob  = Wvb + (size_t)DM * DM;
  bf16* Qw   = Wob + (size_t)DM * DM;       // [4096][1024]  (pre-scaled by QSCALE)
  bf16* Kw   = Qw + (size_t)MTOT * DM;      // [4096][1024]
  bf16* VTw  = Kw + (size_t)MTOT * DM;      // [1024][4096]  (V transposed)
  bf16* Cw   = VTw + (size_t)MTOT * DM;     // [4096][1024]  (context)

  const dim3 blk(256);
  cvt5<<<dim3(1024, 8), blk, 0, stream>>>(Wq, Wk, Wv, Wo, x,
                                          Wqb, Wkb, Wvb, Wob, xb);
  qkv_gemm<<<dim3(32, 8, 3), blk, 0, stream>>>(xb, Wqb, Wkb, Wvb, bq, bk, bv, Qw, Kw, VTw);
  attn<<<dim3(NH * NB, SQ / 128), blk, 0, stream>>>(Qw, Kw, VTw, Cw);
  out_gemm<<<dim3(MTOT / 64, DM / 128), blk, 0, stream>>>(Cw, Wob, bo, out);
}